// Round 12
// baseline (489.494 us; speedup 1.0000x reference)
//
#include <hip/hip_runtime.h>
#include <hip/hip_fp16.h>
#include <math.h>

// ---------------------------------------------------------------------------
// GCN (2->64->32) + edge MLP (65->16->1), N=100k, E=1.6M.
// R8 (4th resubmit; GPU unavailable 4 rounds): k_edge in CSR (col-sorted)
//   slot order with per-XCD col-windows. fill also emits per-slot records
//   (row, col, eid, ea) -> k_edge2 streams records; v[col] gathers coalesce
//   (sorted cols); u table (3.2MB) + v window (0.4MB) fit a 4MB per-XCD L2
//   via blockIdx&7 windowing. out[eid] write becomes scattered (~8x line
//   amp) -- net ~4x fewer bytes for the edge pass.
// ---------------------------------------------------------------------------

__global__ void k_count(const int* __restrict__ col, int* __restrict__ deg, int E) {
    int stride = gridDim.x * blockDim.x;
    for (int e = blockIdx.x * blockDim.x + threadIdx.x; e < E; e += stride)
        atomicAdd(deg + col[e], 1);
}

__global__ void k_scan1(const int* __restrict__ deg, int* __restrict__ start,
                        int* __restrict__ bsum, int N) {
    __shared__ int sd[256];
    int t = threadIdx.x;
    int n = blockIdx.x * 256 + t;
    int d = (n < N) ? deg[n] : 0;
    sd[t] = d;
    __syncthreads();
    for (int off = 1; off < 256; off <<= 1) {
        int tv = (t >= off) ? sd[t - off] : 0;
        __syncthreads();
        sd[t] += tv;
        __syncthreads();
    }
    if (n < N) start[n] = sd[t] - d;
    if (t == 255) bsum[blockIdx.x] = sd[255];
}

__global__ void k_scan2(int* __restrict__ bsum, int nb) {
    __shared__ int sd[512];
    int t = threadIdx.x;
    int d = (t < nb) ? bsum[t] : 0;
    sd[t] = d;
    __syncthreads();
    for (int off = 1; off < 512; off <<= 1) {
        int tv = (t >= off) ? sd[t - off] : 0;
        __syncthreads();
        sd[t] += tv;
        __syncthreads();
    }
    if (t < nb) bsum[t] = sd[t] - d;
}

__global__ void k_scan3(int* __restrict__ start, const int* __restrict__ bsum,
                        int* __restrict__ cursor, const int* __restrict__ deg,
                        const float* __restrict__ x, float* __restrict__ dinv,
                        float* __restrict__ xs, int N) {
    int n = blockIdx.x * 256 + threadIdx.x;
    if (n >= N) return;
    int s = start[n] + bsum[blockIdx.x];
    start[n] = s;
    cursor[n] = s;
    float di = rsqrtf((float)deg[n] + 1.0f);
    dinv[n] = di;
    xs[2 * n] = x[2 * n] * di;
    xs[2 * n + 1] = x[2 * n + 1] * di;
}

// phase-windowed fill; emits full per-slot edge records
__global__ void k_fill(const int* __restrict__ row, const int* __restrict__ col,
                       const float* __restrict__ ea,
                       int* __restrict__ cursor, int* __restrict__ srcidx,
                       int* __restrict__ colv, int* __restrict__ eidv,
                       float* __restrict__ eav,
                       int E, int wshift, int nph) {
    int stride = gridDim.x * blockDim.x;
    int tid0 = blockIdx.x * blockDim.x + threadIdx.x;
    for (int ph = 0; ph < nph; ++ph) {
        for (int e = tid0; e < E; e += stride) {
            int c = col[e];
            if ((c >> wshift) == ph) {
                int p = atomicAdd(cursor + c, 1);
                srcidx[p] = row[e];
                colv[p]   = c;
                eidv[p]   = e;
                eav[p]    = ea[e];
            }
        }
    }
}

// per node: agg xs (+self), *dinv, W1+b1, relu, W2, *dinv -> hs2h (fp16)
__global__ void k_l1l2(const int* __restrict__ start, const int* __restrict__ deg,
                       const int* __restrict__ srcidx,
                       const float* __restrict__ xs, const float* __restrict__ dinv,
                       const float* __restrict__ W1, const float* __restrict__ b1,
                       const float* __restrict__ W2,
                       __half* __restrict__ hs2h, int N) {
    __shared__ float sW1[128], sb1[64], sW2[2048];
    for (int i = threadIdx.x; i < 128;  i += blockDim.x) sW1[i] = W1[i];
    for (int i = threadIdx.x; i < 64;   i += blockDim.x) sb1[i] = b1[i];
    for (int i = threadIdx.x; i < 2048; i += blockDim.x) sW2[i] = W2[i];
    __syncthreads();
    int n = blockIdx.x * 256 + threadIdx.x;
    if (n >= N) return;
    int s = start[n], cnt = deg[n];
    float a0 = xs[2 * n], a1 = xs[2 * n + 1];
    for (int k = 0; k < cnt; ++k) {
        int r = srcidx[s + k];
        a0 += xs[2 * r];
        a1 += xs[2 * r + 1];
    }
    float di = dinv[n];
    a0 *= di; a1 *= di;
    float acc[32];
#pragma unroll
    for (int j = 0; j < 32; ++j) acc[j] = 0.0f;
    for (int k = 0; k < 64; ++k) {
        float h = fmaxf(fmaf(a0, sW1[k], fmaf(a1, sW1[64 + k], sb1[k])), 0.0f);
#pragma unroll
        for (int j = 0; j < 32; ++j) acc[j] = fmaf(h, sW2[k * 32 + j], acc[j]);
    }
    __half2 hb[16];
#pragma unroll
    for (int j = 0; j < 16; ++j)
        hb[j] = __floats2half2_rn(acc[2 * j] * di, acc[2 * j + 1] * di);
    float4* op = (float4*)(hs2h + (size_t)n * 32);
    const float4* ip = (const float4*)hb;
#pragma unroll
    for (int q = 0; q < 4; ++q) op[q] = ip[q];
}

// 32 lanes/node: gather-sum hs2h rows -> h2=relu(sum*dinv+b2) -> LDS,
// then u16 = h2@A, v16 = h2@B (fp16 outputs)
__global__ void k_agg2uv(const int* __restrict__ start, const int* __restrict__ deg,
                         const int* __restrict__ srcidx,
                         const __half* __restrict__ hs2h, const float* __restrict__ dinv,
                         const float* __restrict__ b2, const float* __restrict__ mW1,
                         __half* __restrict__ u16, __half* __restrict__ v16, int N) {
    __shared__ float sA[512], sB[512], sb2[32];
    __shared__ float h2s[8][32];
    for (int i = threadIdx.x; i < 512; i += 256) { sA[i] = mW1[i]; sB[i] = mW1[512 + i]; }
    if (threadIdx.x < 32) sb2[threadIdx.x] = b2[threadIdx.x];
    __syncthreads();
    int g  = threadIdx.x >> 5;
    int ch = threadIdx.x & 31;
    int n  = blockIdx.x * 8 + g;
    if (n < N) {
        int s = start[n], cnt = deg[n];
        float acc = __half2float(hs2h[(size_t)n * 32 + ch]);   // self loop
        for (int k = 0; k < cnt; ++k) {
            int r = srcidx[s + k];
            acc += __half2float(hs2h[(size_t)r * 32 + ch]);
        }
        h2s[g][ch] = fmaxf(fmaf(acc, dinv[n], sb2[ch]), 0.0f);
    }
    __syncthreads();
    if (n >= N) return;
    const float* M = (ch < 16) ? sA : sB;
    int i = ch & 15;
    float s0 = 0.0f;
#pragma unroll
    for (int j = 0; j < 32; ++j) s0 = fmaf(h2s[g][j], M[j * 16 + i], s0);
    if (ch < 16) u16[(size_t)n * 16 + i] = __float2half_rn(s0);
    else         v16[(size_t)n * 16 + i] = __float2half_rn(s0);
}

__device__ inline void unpack8(const float4 f, float* o) {
    const __half2* h2 = (const __half2*)&f;
#pragma unroll
    for (int i = 0; i < 4; ++i) {
        float2 t = __half22float2(h2[i]);
        o[2 * i] = t.x; o[2 * i + 1] = t.y;
    }
}

// CSR-order edge MLP. blockIdx&7 selects a col-window (per-XCD L2 locality):
// u table (3.2MB) + v window (0.4MB) resident per XCD; v gathers coalesce
// because consecutive slots share col. out[eid] is scattered.
__global__ void k_edge2(const int* __restrict__ start,
                        const int* __restrict__ srcidx, const int* __restrict__ colv,
                        const int* __restrict__ eidv, const float* __restrict__ eav,
                        const __half* __restrict__ u16, const __half* __restrict__ v16,
                        const float* __restrict__ mW1, const float* __restrict__ mb1,
                        const float* __restrict__ mW2, const float* __restrict__ mb2,
                        float* __restrict__ out, int N, int E, int Wn) {
    __shared__ float sC[16], sb1[16], sW2v[16], sb2s;
    if (threadIdx.x < 16) {
        sC[threadIdx.x]   = mW1[64 * 16 + threadIdx.x];
        sb1[threadIdx.x]  = mb1[threadIdx.x];
        sW2v[threadIdx.x] = mW2[threadIdx.x];
    }
    if (threadIdx.x == 0) sb2s = mb2[0];
    __syncthreads();
    int xcd = blockIdx.x & 7;
    int grp = blockIdx.x >> 3;                    // block ordinal within window
    int n0 = xcd * Wn;       if (n0 > N) n0 = N;
    int n1 = n0 + Wn;        if (n1 > N) n1 = N;
    int s0 = (n0 < N) ? start[n0] : E;
    int s1 = (n1 < N) ? start[n1] : E;
    int stride = (gridDim.x >> 3) * blockDim.x;   // threads in this window group
    for (int p = s0 + grp * blockDim.x + threadIdx.x; p < s1; p += stride) {
        int r = srcidx[p], c = colv[p], e = eidv[p];
        float a = eav[p];
        const float4* up = (const float4*)(u16 + (size_t)r * 16);
        const float4* vp = (const float4*)(v16 + (size_t)c * 16);
        float4 u0 = up[0], u1 = up[1];
        float4 v0 = vp[0], v1 = vp[1];
        float uf[16], vf[16];
        unpack8(u0, uf); unpack8(u1, uf + 8);
        unpack8(v0, vf); unpack8(v1, vf + 8);
        float s = sb2s;
#pragma unroll
        for (int i = 0; i < 16; ++i) {
            float h = fmaxf(uf[i] + vf[i] + fmaf(a, sC[i], sb1[i]), 0.0f);
            s = fmaf(h, sW2v[i], s);
        }
        out[e] = 1.0f / (1.0f + expf(-s));
    }
}

extern "C" void kernel_launch(void* const* d_in, const int* in_sizes, int n_in,
                              void* d_out, int out_size, void* d_ws, size_t ws_size,
                              hipStream_t stream) {
    const float* x   = (const float*)d_in[0];
    const int*   ei  = (const int*)d_in[1];
    const float* ea  = (const float*)d_in[2];
    const float* W1  = (const float*)d_in[4];
    const float* b1  = (const float*)d_in[5];
    const float* W2  = (const float*)d_in[6];
    const float* b2  = (const float*)d_in[7];
    const float* mW1 = (const float*)d_in[8];
    const float* mb1 = (const float*)d_in[9];
    const float* mW2 = (const float*)d_in[10];
    const float* mb2 = (const float*)d_in[11];
    float* out = (float*)d_out;

    int N = in_sizes[0] / 2;
    int E = in_sizes[2];
    const int* row = ei;
    const int* col = ei + E;

    int clog = 0; while ((1u << clog) < (unsigned)N) ++clog;
    int wshift = clog > 3 ? clog - 3 : 0;
    int nph = ((N - 1) >> wshift) + 1;
    int Wn = (N + 7) / 8;                // per-XCD col window (nodes)

    int* deg    = (int*)d_ws;            // N
    int* start  = deg + N;               // N
    int* cursor = start + N;             // N
    int* bsum   = cursor + N;            // 1024
    int* srcidx = bsum + 1024;           // E
    int* colv   = srcidx + E;            // E
    int* eidv   = colv + E;              // E
    float* eav  = (float*)(eidv + E);    // E
    float* dinv = eav + (size_t)E;       // N
    float* xs   = dinv + (size_t)N;      // 2N
    __half* hs2h = (__half*)(xs + (size_t)2 * N);   // 32N halves
    __half* u16  = hs2h + (size_t)32 * N;           // 16N halves
    __half* v16  = u16 + (size_t)16 * N;            // 16N halves

    int nb_n = (N + 255) / 256;

    hipMemsetAsync(deg, 0, (size_t)N * sizeof(int), stream);
    k_count<<<2048, 256, 0, stream>>>(col, deg, E);
    k_scan1<<<nb_n, 256, 0, stream>>>(deg, start, bsum, N);
    k_scan2<<<1, 512, 0, stream>>>(bsum, nb_n);
    k_scan3<<<nb_n, 256, 0, stream>>>(start, bsum, cursor, deg, x, dinv, xs, N);
    k_fill <<<2048, 256, 0, stream>>>(row, col, ea, cursor, srcidx, colv, eidv, eav,
                                      E, wshift, nph);
    k_l1l2 <<<nb_n, 256, 0, stream>>>(start, deg, srcidx, xs, dinv, W1, b1, W2, hs2h, N);
    k_agg2uv<<<(N + 7) / 8, 256, 0, stream>>>(start, deg, srcidx, hs2h, dinv, b2, mW1, u16, v16, N);
    k_edge2<<<2048, 256, 0, stream>>>(start, srcidx, colv, eidv, eav, u16, v16,
                                      mW1, mb1, mW2, mb2, out, N, E, Wn);
}

// Round 13
// 390.265 us; speedup vs baseline: 1.2543x; 1.2543x over previous
//
#include <hip/hip_runtime.h>
#include <hip/hip_fp16.h>
#include <math.h>

// ---------------------------------------------------------------------------
// GCN (2->64->32) + edge MLP (65->16->1), N=100k, E=1.6M.
// R13: revert R8's CSR-ordered edge pass (out[eid] scatter cost write-
//   allocate FETCH + cross-XCD writebacks; records thrashed u out of L2).
//   Keep R7 edge-ordered k_edge (113us best) with 2-edge ILP for latency.
//   Fix k_fill cross-XCD false sharing: phase = blockIdx&7 (XCD-exclusive
//   windows) -> each srcidx line dirty in ~1 L2, writeback ~= data size.
// ---------------------------------------------------------------------------

__global__ void k_count(const int* __restrict__ col, int* __restrict__ deg, int E) {
    int stride = gridDim.x * blockDim.x;
    for (int e = blockIdx.x * blockDim.x + threadIdx.x; e < E; e += stride)
        atomicAdd(deg + col[e], 1);
}

__global__ void k_scan1(const int* __restrict__ deg, int* __restrict__ start,
                        int* __restrict__ bsum, int N) {
    __shared__ int sd[256];
    int t = threadIdx.x;
    int n = blockIdx.x * 256 + t;
    int d = (n < N) ? deg[n] : 0;
    sd[t] = d;
    __syncthreads();
    for (int off = 1; off < 256; off <<= 1) {
        int tv = (t >= off) ? sd[t - off] : 0;
        __syncthreads();
        sd[t] += tv;
        __syncthreads();
    }
    if (n < N) start[n] = sd[t] - d;
    if (t == 255) bsum[blockIdx.x] = sd[255];
}

__global__ void k_scan2(int* __restrict__ bsum, int nb) {
    __shared__ int sd[512];
    int t = threadIdx.x;
    int d = (t < nb) ? bsum[t] : 0;
    sd[t] = d;
    __syncthreads();
    for (int off = 1; off < 512; off <<= 1) {
        int tv = (t >= off) ? sd[t - off] : 0;
        __syncthreads();
        sd[t] += tv;
        __syncthreads();
    }
    if (t < nb) bsum[t] = sd[t] - d;
}

__global__ void k_scan3(int* __restrict__ start, const int* __restrict__ bsum,
                        int* __restrict__ cursor, const int* __restrict__ deg,
                        const float* __restrict__ x, float* __restrict__ dinv,
                        float* __restrict__ xs, int N) {
    int n = blockIdx.x * 256 + threadIdx.x;
    if (n >= N) return;
    int s = start[n] + bsum[blockIdx.x];
    start[n] = s;
    cursor[n] = s;
    float di = rsqrtf((float)deg[n] + 1.0f);
    dinv[n] = di;
    xs[2 * n] = x[2 * n] * di;
    xs[2 * n + 1] = x[2 * n + 1] * di;
}

// XCD-exclusive windowed fill: block group g = blockIdx&7 handles phases
// ph ≡ g (mod 8); each phase's srcidx window written by one XCD class only.
__global__ void k_fill(const int* __restrict__ row, const int* __restrict__ col,
                       int* __restrict__ cursor, int* __restrict__ srcidx,
                       int E, int wshift, int nph) {
    int g      = blockIdx.x & 7;
    int tid0   = (blockIdx.x >> 3) * blockDim.x + threadIdx.x;
    int stride = (gridDim.x >> 3) * blockDim.x;
    for (int ph = g; ph < nph; ph += 8) {
        for (int e = tid0; e < E; e += stride) {
            int c = col[e];
            if ((c >> wshift) == ph) {
                int p = atomicAdd(cursor + c, 1);
                srcidx[p] = row[e];
            }
        }
    }
}

// per node: agg xs (+self), *dinv, W1+b1, relu, W2, *dinv -> hs2h (fp16)
__global__ void k_l1l2(const int* __restrict__ start, const int* __restrict__ deg,
                       const int* __restrict__ srcidx,
                       const float* __restrict__ xs, const float* __restrict__ dinv,
                       const float* __restrict__ W1, const float* __restrict__ b1,
                       const float* __restrict__ W2,
                       __half* __restrict__ hs2h, int N) {
    __shared__ float sW1[128], sb1[64], sW2[2048];
    for (int i = threadIdx.x; i < 128;  i += blockDim.x) sW1[i] = W1[i];
    for (int i = threadIdx.x; i < 64;   i += blockDim.x) sb1[i] = b1[i];
    for (int i = threadIdx.x; i < 2048; i += blockDim.x) sW2[i] = W2[i];
    __syncthreads();
    int n = blockIdx.x * 256 + threadIdx.x;
    if (n >= N) return;
    int s = start[n], cnt = deg[n];
    float a0 = xs[2 * n], a1 = xs[2 * n + 1];
    for (int k = 0; k < cnt; ++k) {
        int r = srcidx[s + k];
        a0 += xs[2 * r];
        a1 += xs[2 * r + 1];
    }
    float di = dinv[n];
    a0 *= di; a1 *= di;
    float acc[32];
#pragma unroll
    for (int j = 0; j < 32; ++j) acc[j] = 0.0f;
    for (int k = 0; k < 64; ++k) {
        float h = fmaxf(fmaf(a0, sW1[k], fmaf(a1, sW1[64 + k], sb1[k])), 0.0f);
#pragma unroll
        for (int j = 0; j < 32; ++j) acc[j] = fmaf(h, sW2[k * 32 + j], acc[j]);
    }
    __half2 hb[16];
#pragma unroll
    for (int j = 0; j < 16; ++j)
        hb[j] = __floats2half2_rn(acc[2 * j] * di, acc[2 * j + 1] * di);
    float4* op = (float4*)(hs2h + (size_t)n * 32);
    const float4* ip = (const float4*)hb;
#pragma unroll
    for (int q = 0; q < 4; ++q) op[q] = ip[q];
}

// 32 lanes/node: gather-sum hs2h rows -> h2=relu(sum*dinv+b2) -> LDS,
// then u16 = h2@A, v16 = h2@B (fp16 outputs)
__global__ void k_agg2uv(const int* __restrict__ start, const int* __restrict__ deg,
                         const int* __restrict__ srcidx,
                         const __half* __restrict__ hs2h, const float* __restrict__ dinv,
                         const float* __restrict__ b2, const float* __restrict__ mW1,
                         __half* __restrict__ u16, __half* __restrict__ v16, int N) {
    __shared__ float sA[512], sB[512], sb2[32];
    __shared__ float h2s[8][32];
    for (int i = threadIdx.x; i < 512; i += 256) { sA[i] = mW1[i]; sB[i] = mW1[512 + i]; }
    if (threadIdx.x < 32) sb2[threadIdx.x] = b2[threadIdx.x];
    __syncthreads();
    int g  = threadIdx.x >> 5;
    int ch = threadIdx.x & 31;
    int n  = blockIdx.x * 8 + g;
    if (n < N) {
        int s = start[n], cnt = deg[n];
        float acc = __half2float(hs2h[(size_t)n * 32 + ch]);   // self loop
        for (int k = 0; k < cnt; ++k) {
            int r = srcidx[s + k];
            acc += __half2float(hs2h[(size_t)r * 32 + ch]);
        }
        h2s[g][ch] = fmaxf(fmaf(acc, dinv[n], sb2[ch]), 0.0f);
    }
    __syncthreads();
    if (n >= N) return;
    const float* M = (ch < 16) ? sA : sB;
    int i = ch & 15;
    float s0 = 0.0f;
#pragma unroll
    for (int j = 0; j < 32; ++j) s0 = fmaf(h2s[g][j], M[j * 16 + i], s0);
    if (ch < 16) u16[(size_t)n * 16 + i] = __float2half_rn(s0);
    else         v16[(size_t)n * 16 + i] = __float2half_rn(s0);
}

__device__ inline void unpack8(const float4 f, float* o) {
    const __half2* h2 = (const __half2*)&f;
#pragma unroll
    for (int i = 0; i < 4; ++i) {
        float2 t = __half22float2(h2[i]);
        o[2 * i] = t.x; o[2 * i + 1] = t.y;
    }
}

// edge-order MLP, 2 edges per thread per iteration (ILP for gather latency)
__global__ void k_edge(const int* __restrict__ row, const int* __restrict__ col,
                       const float* __restrict__ ea,
                       const __half* __restrict__ u16, const __half* __restrict__ v16,
                       const float* __restrict__ mW1, const float* __restrict__ mb1,
                       const float* __restrict__ mW2, const float* __restrict__ mb2,
                       float* __restrict__ out, int E) {
    __shared__ float sC[16], sb1[16], sW2v[16], sb2s;
    if (threadIdx.x < 16) {
        sC[threadIdx.x]   = mW1[64 * 16 + threadIdx.x];
        sb1[threadIdx.x]  = mb1[threadIdx.x];
        sW2v[threadIdx.x] = mW2[threadIdx.x];
    }
    if (threadIdx.x == 0) sb2s = mb2[0];
    __syncthreads();
    int tid    = blockIdx.x * blockDim.x + threadIdx.x;
    int stride = gridDim.x * blockDim.x;
    for (int e0 = tid * 2; e0 < E; e0 += stride * 2) {
        int e1 = e0 + 1;
        bool two = (e1 < E);
        int2 r2 = *(const int2*)(row + e0);
        int2 c2 = *(const int2*)(col + e0);
        float2 a2 = *(const float2*)(ea + e0);
        const float4* up0 = (const float4*)(u16 + (size_t)r2.x * 16);
        const float4* vp0 = (const float4*)(v16 + (size_t)c2.x * 16);
        const float4* up1 = (const float4*)(u16 + (size_t)r2.y * 16);
        const float4* vp1 = (const float4*)(v16 + (size_t)c2.y * 16);
        float4 ua0 = up0[0], ub0 = up0[1];
        float4 va0 = vp0[0], vb0 = vp0[1];
        float4 ua1 = up1[0], ub1 = up1[1];
        float4 va1 = vp1[0], vb1 = vp1[1];
        float uf0[16], vf0[16], uf1[16], vf1[16];
        unpack8(ua0, uf0); unpack8(ub0, uf0 + 8);
        unpack8(va0, vf0); unpack8(vb0, vf0 + 8);
        unpack8(ua1, uf1); unpack8(ub1, uf1 + 8);
        unpack8(va1, vf1); unpack8(vb1, vf1 + 8);
        float s0 = sb2s, s1 = sb2s;
#pragma unroll
        for (int i = 0; i < 16; ++i) {
            float t0 = fmaf(a2.x, sC[i], sb1[i]);
            float t1 = fmaf(a2.y, sC[i], sb1[i]);
            float h0 = fmaxf(uf0[i] + vf0[i] + t0, 0.0f);
            float h1 = fmaxf(uf1[i] + vf1[i] + t1, 0.0f);
            s0 = fmaf(h0, sW2v[i], s0);
            s1 = fmaf(h1, sW2v[i], s1);
        }
        float o0 = 1.0f / (1.0f + expf(-s0));
        float o1 = 1.0f / (1.0f + expf(-s1));
        if (two) {
            *(float2*)(out + e0) = make_float2(o0, o1);
        } else {
            out[e0] = o0;
        }
    }
}

extern "C" void kernel_launch(void* const* d_in, const int* in_sizes, int n_in,
                              void* d_out, int out_size, void* d_ws, size_t ws_size,
                              hipStream_t stream) {
    const float* x   = (const float*)d_in[0];
    const int*   ei  = (const int*)d_in[1];
    const float* ea  = (const float*)d_in[2];
    const float* W1  = (const float*)d_in[4];
    const float* b1  = (const float*)d_in[5];
    const float* W2  = (const float*)d_in[6];
    const float* b2  = (const float*)d_in[7];
    const float* mW1 = (const float*)d_in[8];
    const float* mb1 = (const float*)d_in[9];
    const float* mW2 = (const float*)d_in[10];
    const float* mb2 = (const float*)d_in[11];
    float* out = (float*)d_out;

    int N = in_sizes[0] / 2;
    int E = in_sizes[2];
    const int* row = ei;
    const int* col = ei + E;

    int clog = 0; while ((1u << clog) < (unsigned)N) ++clog;
    int wshift = clog > 3 ? clog - 3 : 0;
    int nph = ((N - 1) >> wshift) + 1;

    int* deg    = (int*)d_ws;            // N
    int* start  = deg + N;               // N
    int* cursor = start + N;             // N
    int* bsum   = cursor + N;            // 1024
    int* srcidx = bsum + 1024;           // E
    float* dinv = (float*)(srcidx + E);  // N
    float* xs   = dinv + (size_t)N;      // 2N
    __half* hs2h = (__half*)(xs + (size_t)2 * N);   // 32N halves
    __half* u16  = hs2h + (size_t)32 * N;           // 16N halves
    __half* v16  = u16 + (size_t)16 * N;            // 16N halves

    int nb_n = (N + 255) / 256;

    hipMemsetAsync(deg, 0, (size_t)N * sizeof(int), stream);
    k_count<<<2048, 256, 0, stream>>>(col, deg, E);
    k_scan1<<<nb_n, 256, 0, stream>>>(deg, start, bsum, N);
    k_scan2<<<1, 512, 0, stream>>>(bsum, nb_n);
    k_scan3<<<nb_n, 256, 0, stream>>>(start, bsum, cursor, deg, x, dinv, xs, N);
    k_fill <<<2048, 256, 0, stream>>>(row, col, cursor, srcidx, E, wshift, nph);
    k_l1l2 <<<nb_n, 256, 0, stream>>>(start, deg, srcidx, xs, dinv, W1, b1, W2, hs2h, N);
    k_agg2uv<<<(N + 7) / 8, 256, 0, stream>>>(start, deg, srcidx, hs2h, dinv, b2, mW1, u16, v16, N);
    k_edge <<<2048, 256, 0, stream>>>(row, col, ea, u16, v16, mW1, mb1, mW2, mb2, out, E);
}

// Round 14
// 365.767 us; speedup vs baseline: 1.3383x; 1.0670x over previous
//
#include <hip/hip_runtime.h>
#include <hip/hip_fp16.h>
#include <math.h>

// ---------------------------------------------------------------------------
// GCN (2->64->32) + edge MLP (65->16->1), N=100k, E=1.6M.
// R14: k_agg2uv was latency-bound (serial 32-lane gather chain + LDS h2
//   staging, 3.2M bank conflicts). Rewrite: one 64-lane wave per node;
//   halves process edges k/k+1 (2-deep unroll = 4 gathers in flight);
//   __shfl_xor(32) combines halves -- no LDS h2, no barriers, 0 conflicts.
//   Matmul uses all 64 lanes (j-split across halves + shfl broadcast).
// ---------------------------------------------------------------------------

__global__ void k_count(const int* __restrict__ col, int* __restrict__ deg, int E) {
    int stride = gridDim.x * blockDim.x;
    for (int e = blockIdx.x * blockDim.x + threadIdx.x; e < E; e += stride)
        atomicAdd(deg + col[e], 1);
}

__global__ void k_scan1(const int* __restrict__ deg, int* __restrict__ start,
                        int* __restrict__ bsum, int N) {
    __shared__ int sd[256];
    int t = threadIdx.x;
    int n = blockIdx.x * 256 + t;
    int d = (n < N) ? deg[n] : 0;
    sd[t] = d;
    __syncthreads();
    for (int off = 1; off < 256; off <<= 1) {
        int tv = (t >= off) ? sd[t - off] : 0;
        __syncthreads();
        sd[t] += tv;
        __syncthreads();
    }
    if (n < N) start[n] = sd[t] - d;
    if (t == 255) bsum[blockIdx.x] = sd[255];
}

__global__ void k_scan2(int* __restrict__ bsum, int nb) {
    __shared__ int sd[512];
    int t = threadIdx.x;
    int d = (t < nb) ? bsum[t] : 0;
    sd[t] = d;
    __syncthreads();
    for (int off = 1; off < 512; off <<= 1) {
        int tv = (t >= off) ? sd[t - off] : 0;
        __syncthreads();
        sd[t] += tv;
        __syncthreads();
    }
    if (t < nb) bsum[t] = sd[t] - d;
}

__global__ void k_scan3(int* __restrict__ start, const int* __restrict__ bsum,
                        int* __restrict__ cursor, const int* __restrict__ deg,
                        const float* __restrict__ x, float* __restrict__ dinv,
                        float* __restrict__ xs, int N) {
    int n = blockIdx.x * 256 + threadIdx.x;
    if (n >= N) return;
    int s = start[n] + bsum[blockIdx.x];
    start[n] = s;
    cursor[n] = s;
    float di = rsqrtf((float)deg[n] + 1.0f);
    dinv[n] = di;
    xs[2 * n] = x[2 * n] * di;
    xs[2 * n + 1] = x[2 * n + 1] * di;
}

// XCD-exclusive windowed fill (R13, verified): phase ph ≡ blockIdx&7 (mod 8)
__global__ void k_fill(const int* __restrict__ row, const int* __restrict__ col,
                       int* __restrict__ cursor, int* __restrict__ srcidx,
                       int E, int wshift, int nph) {
    int g      = blockIdx.x & 7;
    int tid0   = (blockIdx.x >> 3) * blockDim.x + threadIdx.x;
    int stride = (gridDim.x >> 3) * blockDim.x;
    for (int ph = g; ph < nph; ph += 8) {
        for (int e = tid0; e < E; e += stride) {
            int c = col[e];
            if ((c >> wshift) == ph) {
                int p = atomicAdd(cursor + c, 1);
                srcidx[p] = row[e];
            }
        }
    }
}

// per node: agg xs (+self), *dinv, W1+b1, relu, W2, *dinv -> hs2h (fp16)
__global__ void k_l1l2(const int* __restrict__ start, const int* __restrict__ deg,
                       const int* __restrict__ srcidx,
                       const float* __restrict__ xs, const float* __restrict__ dinv,
                       const float* __restrict__ W1, const float* __restrict__ b1,
                       const float* __restrict__ W2,
                       __half* __restrict__ hs2h, int N) {
    __shared__ float sW1[128], sb1[64], sW2[2048];
    for (int i = threadIdx.x; i < 128;  i += blockDim.x) sW1[i] = W1[i];
    for (int i = threadIdx.x; i < 64;   i += blockDim.x) sb1[i] = b1[i];
    for (int i = threadIdx.x; i < 2048; i += blockDim.x) sW2[i] = W2[i];
    __syncthreads();
    int n = blockIdx.x * 256 + threadIdx.x;
    if (n >= N) return;
    int s = start[n], cnt = deg[n];
    float a0 = xs[2 * n], a1 = xs[2 * n + 1];
    for (int k = 0; k < cnt; ++k) {
        int r = srcidx[s + k];
        a0 += xs[2 * r];
        a1 += xs[2 * r + 1];
    }
    float di = dinv[n];
    a0 *= di; a1 *= di;
    float acc[32];
#pragma unroll
    for (int j = 0; j < 32; ++j) acc[j] = 0.0f;
    for (int k = 0; k < 64; ++k) {
        float h = fmaxf(fmaf(a0, sW1[k], fmaf(a1, sW1[64 + k], sb1[k])), 0.0f);
#pragma unroll
        for (int j = 0; j < 32; ++j) acc[j] = fmaf(h, sW2[k * 32 + j], acc[j]);
    }
    __half2 hb[16];
#pragma unroll
    for (int j = 0; j < 16; ++j)
        hb[j] = __floats2half2_rn(acc[2 * j] * di, acc[2 * j + 1] * di);
    float4* op = (float4*)(hs2h + (size_t)n * 32);
    const float4* ip = (const float4*)hb;
#pragma unroll
    for (int q = 0; q < 4; ++q) op[q] = ip[q];
}

// one 64-lane wave per node; halves h=0/1 gather edges k/k+1; shfl combine
__global__ void k_agg2uv(const int* __restrict__ start, const int* __restrict__ deg,
                         const int* __restrict__ srcidx,
                         const __half* __restrict__ hs2h, const float* __restrict__ dinv,
                         const float* __restrict__ b2, const float* __restrict__ mW1,
                         __half* __restrict__ u16, __half* __restrict__ v16, int N) {
    __shared__ float sA[512], sB[512], sb2[32];
    for (int i = threadIdx.x; i < 512; i += 256) { sA[i] = mW1[i]; sB[i] = mW1[512 + i]; }
    if (threadIdx.x < 32) sb2[threadIdx.x] = b2[threadIdx.x];
    __syncthreads();
    int L  = threadIdx.x & 63;           // lane in wave
    int w  = threadIdx.x >> 6;           // wave in block (4 waves)
    int ch = L & 31;                     // channel
    int h  = L >> 5;                     // half: edge parity
    int n  = blockIdx.x * 4 + w;
    if (n >= N) return;

    int s = start[n], cnt = deg[n];
    float acc0 = (h == 0) ? __half2float(hs2h[(size_t)n * 32 + ch]) : 0.0f;  // self
    float acc1 = 0.0f;
    int k = 0;
    for (; k + 3 < cnt; k += 4) {
        int ra = srcidx[s + k + h];
        int rb = srcidx[s + k + 2 + h];
        acc0 += __half2float(hs2h[(size_t)ra * 32 + ch]);
        acc1 += __half2float(hs2h[(size_t)rb * 32 + ch]);
    }
    for (; k + 1 < cnt; k += 2) {
        int r = srcidx[s + k + h];
        acc0 += __half2float(hs2h[(size_t)r * 32 + ch]);
    }
    if (k < cnt && h == 0) {             // odd tail: lower half only
        int r = srcidx[s + k];
        acc0 += __half2float(hs2h[(size_t)r * 32 + ch]);
    }
    float acc = acc0 + acc1;
    acc += __shfl_xor(acc, 32);          // combine halves: all lanes have sum(ch)
    float h2 = fmaxf(fmaf(acc, dinv[n], sb2[ch]), 0.0f);

    // matmul: 64 lanes = 2 j-halves x (16 u-outputs + 16 v-outputs)
    int jh = L >> 5;                     // j-half
    int os = (L >> 4) & 1;               // 0 -> u, 1 -> v
    int i  = L & 15;                     // output index
    const float* M = os ? sB : sA;
    float part = 0.0f;
#pragma unroll
    for (int t = 0; t < 16; ++t) {
        int j = jh * 16 + t;
        float hj = __shfl(h2, j);        // h2[j] lives in lane j (ch==j)
        part = fmaf(hj, M[j * 16 + i], part);
    }
    part += __shfl_xor(part, 32);        // sum the two j-halves
    if (L < 32) {
        __half val = __float2half_rn(part);
        if (os == 0) u16[(size_t)n * 16 + i] = val;
        else         v16[(size_t)n * 16 + i] = val;
    }
}

__device__ inline void unpack8(const float4 f, float* o) {
    const __half2* h2 = (const __half2*)&f;
#pragma unroll
    for (int i = 0; i < 4; ++i) {
        float2 t = __half22float2(h2[i]);
        o[2 * i] = t.x; o[2 * i + 1] = t.y;
    }
}

// edge-order MLP, 2 edges per thread per iteration (ILP for gather latency)
__global__ void k_edge(const int* __restrict__ row, const int* __restrict__ col,
                       const float* __restrict__ ea,
                       const __half* __restrict__ u16, const __half* __restrict__ v16,
                       const float* __restrict__ mW1, const float* __restrict__ mb1,
                       const float* __restrict__ mW2, const float* __restrict__ mb2,
                       float* __restrict__ out, int E) {
    __shared__ float sC[16], sb1[16], sW2v[16], sb2s;
    if (threadIdx.x < 16) {
        sC[threadIdx.x]   = mW1[64 * 16 + threadIdx.x];
        sb1[threadIdx.x]  = mb1[threadIdx.x];
        sW2v[threadIdx.x] = mW2[threadIdx.x];
    }
    if (threadIdx.x == 0) sb2s = mb2[0];
    __syncthreads();
    int tid    = blockIdx.x * blockDim.x + threadIdx.x;
    int stride = gridDim.x * blockDim.x;
    for (int e0 = tid * 2; e0 < E; e0 += stride * 2) {
        int e1 = e0 + 1;
        bool two = (e1 < E);
        int2 r2 = *(const int2*)(row + e0);
        int2 c2 = *(const int2*)(col + e0);
        float2 a2 = *(const float2*)(ea + e0);
        const float4* up0 = (const float4*)(u16 + (size_t)r2.x * 16);
        const float4* vp0 = (const float4*)(v16 + (size_t)c2.x * 16);
        const float4* up1 = (const float4*)(u16 + (size_t)r2.y * 16);
        const float4* vp1 = (const float4*)(v16 + (size_t)c2.y * 16);
        float4 ua0 = up0[0], ub0 = up0[1];
        float4 va0 = vp0[0], vb0 = vp0[1];
        float4 ua1 = up1[0], ub1 = up1[1];
        float4 va1 = vp1[0], vb1 = vp1[1];
        float uf0[16], vf0[16], uf1[16], vf1[16];
        unpack8(ua0, uf0); unpack8(ub0, uf0 + 8);
        unpack8(va0, vf0); unpack8(vb0, vf0 + 8);
        unpack8(ua1, uf1); unpack8(ub1, uf1 + 8);
        unpack8(va1, vf1); unpack8(vb1, vf1 + 8);
        float s0 = sb2s, s1 = sb2s;
#pragma unroll
        for (int i = 0; i < 16; ++i) {
            float t0 = fmaf(a2.x, sC[i], sb1[i]);
            float t1 = fmaf(a2.y, sC[i], sb1[i]);
            float h0 = fmaxf(uf0[i] + vf0[i] + t0, 0.0f);
            float h1 = fmaxf(uf1[i] + vf1[i] + t1, 0.0f);
            s0 = fmaf(h0, sW2v[i], s0);
            s1 = fmaf(h1, sW2v[i], s1);
        }
        float o0 = 1.0f / (1.0f + expf(-s0));
        float o1 = 1.0f / (1.0f + expf(-s1));
        if (two) {
            *(float2*)(out + e0) = make_float2(o0, o1);
        } else {
            out[e0] = o0;
        }
    }
}

extern "C" void kernel_launch(void* const* d_in, const int* in_sizes, int n_in,
                              void* d_out, int out_size, void* d_ws, size_t ws_size,
                              hipStream_t stream) {
    const float* x   = (const float*)d_in[0];
    const int*   ei  = (const int*)d_in[1];
    const float* ea  = (const float*)d_in[2];
    const float* W1  = (const float*)d_in[4];
    const float* b1  = (const float*)d_in[5];
    const float* W2  = (const float*)d_in[6];
    const float* b2  = (const float*)d_in[7];
    const float* mW1 = (const float*)d_in[8];
    const float* mb1 = (const float*)d_in[9];
    const float* mW2 = (const float*)d_in[10];
    const float* mb2 = (const float*)d_in[11];
    float* out = (float*)d_out;

    int N = in_sizes[0] / 2;
    int E = in_sizes[2];
    const int* row = ei;
    const int* col = ei + E;

    int clog = 0; while ((1u << clog) < (unsigned)N) ++clog;
    int wshift = clog > 3 ? clog - 3 : 0;
    int nph = ((N - 1) >> wshift) + 1;

    int* deg    = (int*)d_ws;            // N
    int* start  = deg + N;               // N
    int* cursor = start + N;             // N
    int* bsum   = cursor + N;            // 1024
    int* srcidx = bsum + 1024;           // E
    float* dinv = (float*)(srcidx + E);  // N
    float* xs   = dinv + (size_t)N;      // 2N
    __half* hs2h = (__half*)(xs + (size_t)2 * N);   // 32N halves
    __half* u16  = hs2h + (size_t)32 * N;           // 16N halves
    __half* v16  = u16 + (size_t)16 * N;            // 16N halves

    int nb_n = (N + 255) / 256;

    hipMemsetAsync(deg, 0, (size_t)N * sizeof(int), stream);
    k_count<<<2048, 256, 0, stream>>>(col, deg, E);
    k_scan1<<<nb_n, 256, 0, stream>>>(deg, start, bsum, N);
    k_scan2<<<1, 512, 0, stream>>>(bsum, nb_n);
    k_scan3<<<nb_n, 256, 0, stream>>>(start, bsum, cursor, deg, x, dinv, xs, N);
    k_fill <<<2048, 256, 0, stream>>>(row, col, cursor, srcidx, E, wshift, nph);
    k_l1l2 <<<nb_n, 256, 0, stream>>>(start, deg, srcidx, xs, dinv, W1, b1, W2, hs2h, N);
    k_agg2uv<<<(N + 3) / 4, 256, 0, stream>>>(start, deg, srcidx, hs2h, dinv, b2, mW1, u16, v16, N);
    k_edge <<<2048, 256, 0, stream>>>(row, col, ea, u16, v16, mW1, mb1, mW2, mb2, out, E);
}

// Round 15
// 364.239 us; speedup vs baseline: 1.3439x; 1.0042x over previous
//
#include <hip/hip_runtime.h>
#include <hip/hip_fp16.h>
#include <math.h>

// ---------------------------------------------------------------------------
// GCN (2->64->32) + edge MLP (65->16->1), N=100k, E=1.6M.
// R15: (1) agg2uv gather ILP 2->4-deep (8 rows in flight).
//      (2) edge MLP channel-split 2-pass: uA/vA (ch0-7) then uB/vB (ch8-15);
//          each pass's tables = 3.2MB < 4MB per-XCD L2 -> no thrash
//          (R7 evidence: u+v 6.4MB thrashed, FETCH 247MB vs 26 compulsory).
//          Pass A writes partial sum to ws; pass B adds + sigmoid.
// ---------------------------------------------------------------------------

__global__ void k_count(const int* __restrict__ col, int* __restrict__ deg, int E) {
    int stride = gridDim.x * blockDim.x;
    for (int e = blockIdx.x * blockDim.x + threadIdx.x; e < E; e += stride)
        atomicAdd(deg + col[e], 1);
}

__global__ void k_scan1(const int* __restrict__ deg, int* __restrict__ start,
                        int* __restrict__ bsum, int N) {
    __shared__ int sd[256];
    int t = threadIdx.x;
    int n = blockIdx.x * 256 + t;
    int d = (n < N) ? deg[n] : 0;
    sd[t] = d;
    __syncthreads();
    for (int off = 1; off < 256; off <<= 1) {
        int tv = (t >= off) ? sd[t - off] : 0;
        __syncthreads();
        sd[t] += tv;
        __syncthreads();
    }
    if (n < N) start[n] = sd[t] - d;
    if (t == 255) bsum[blockIdx.x] = sd[255];
}

__global__ void k_scan2(int* __restrict__ bsum, int nb) {
    __shared__ int sd[512];
    int t = threadIdx.x;
    int d = (t < nb) ? bsum[t] : 0;
    sd[t] = d;
    __syncthreads();
    for (int off = 1; off < 512; off <<= 1) {
        int tv = (t >= off) ? sd[t - off] : 0;
        __syncthreads();
        sd[t] += tv;
        __syncthreads();
    }
    if (t < nb) bsum[t] = sd[t] - d;
}

__global__ void k_scan3(int* __restrict__ start, const int* __restrict__ bsum,
                        int* __restrict__ cursor, const int* __restrict__ deg,
                        const float* __restrict__ x, float* __restrict__ dinv,
                        float* __restrict__ xs, int N) {
    int n = blockIdx.x * 256 + threadIdx.x;
    if (n >= N) return;
    int s = start[n] + bsum[blockIdx.x];
    start[n] = s;
    cursor[n] = s;
    float di = rsqrtf((float)deg[n] + 1.0f);
    dinv[n] = di;
    xs[2 * n] = x[2 * n] * di;
    xs[2 * n + 1] = x[2 * n + 1] * di;
}

// XCD-exclusive windowed fill (R13, verified)
__global__ void k_fill(const int* __restrict__ row, const int* __restrict__ col,
                       int* __restrict__ cursor, int* __restrict__ srcidx,
                       int E, int wshift, int nph) {
    int g      = blockIdx.x & 7;
    int tid0   = (blockIdx.x >> 3) * blockDim.x + threadIdx.x;
    int stride = (gridDim.x >> 3) * blockDim.x;
    for (int ph = g; ph < nph; ph += 8) {
        for (int e = tid0; e < E; e += stride) {
            int c = col[e];
            if ((c >> wshift) == ph) {
                int p = atomicAdd(cursor + c, 1);
                srcidx[p] = row[e];
            }
        }
    }
}

// per node: agg xs (+self), *dinv, W1+b1, relu, W2, *dinv -> hs2h (fp16)
__global__ void k_l1l2(const int* __restrict__ start, const int* __restrict__ deg,
                       const int* __restrict__ srcidx,
                       const float* __restrict__ xs, const float* __restrict__ dinv,
                       const float* __restrict__ W1, const float* __restrict__ b1,
                       const float* __restrict__ W2,
                       __half* __restrict__ hs2h, int N) {
    __shared__ float sW1[128], sb1[64], sW2[2048];
    for (int i = threadIdx.x; i < 128;  i += blockDim.x) sW1[i] = W1[i];
    for (int i = threadIdx.x; i < 64;   i += blockDim.x) sb1[i] = b1[i];
    for (int i = threadIdx.x; i < 2048; i += blockDim.x) sW2[i] = W2[i];
    __syncthreads();
    int n = blockIdx.x * 256 + threadIdx.x;
    if (n >= N) return;
    int s = start[n], cnt = deg[n];
    float a0 = xs[2 * n], a1 = xs[2 * n + 1];
    for (int k = 0; k < cnt; ++k) {
        int r = srcidx[s + k];
        a0 += xs[2 * r];
        a1 += xs[2 * r + 1];
    }
    float di = dinv[n];
    a0 *= di; a1 *= di;
    float acc[32];
#pragma unroll
    for (int j = 0; j < 32; ++j) acc[j] = 0.0f;
    for (int k = 0; k < 64; ++k) {
        float h = fmaxf(fmaf(a0, sW1[k], fmaf(a1, sW1[64 + k], sb1[k])), 0.0f);
#pragma unroll
        for (int j = 0; j < 32; ++j) acc[j] = fmaf(h, sW2[k * 32 + j], acc[j]);
    }
    __half2 hb[16];
#pragma unroll
    for (int j = 0; j < 16; ++j)
        hb[j] = __floats2half2_rn(acc[2 * j] * di, acc[2 * j + 1] * di);
    float4* op = (float4*)(hs2h + (size_t)n * 32);
    const float4* ip = (const float4*)hb;
#pragma unroll
    for (int q = 0; q < 4; ++q) op[q] = ip[q];
}

// one 64-lane wave per node; halves h=0/1; 4-deep unroll (8 rows in flight);
// outputs split into lo/hi channel tables (uA/uB/vA/vB, 8 ch each)
__global__ void k_agg2uv(const int* __restrict__ start, const int* __restrict__ deg,
                         const int* __restrict__ srcidx,
                         const __half* __restrict__ hs2h, const float* __restrict__ dinv,
                         const float* __restrict__ b2, const float* __restrict__ mW1,
                         __half* __restrict__ uA, __half* __restrict__ uB,
                         __half* __restrict__ vA, __half* __restrict__ vB, int N) {
    __shared__ float sA[512], sB[512], sb2[32];
    for (int i = threadIdx.x; i < 512; i += 256) { sA[i] = mW1[i]; sB[i] = mW1[512 + i]; }
    if (threadIdx.x < 32) sb2[threadIdx.x] = b2[threadIdx.x];
    __syncthreads();
    int L  = threadIdx.x & 63;
    int w  = threadIdx.x >> 6;
    int ch = L & 31;
    int h  = L >> 5;
    int n  = blockIdx.x * 4 + w;
    if (n >= N) return;

    int s = start[n], cnt = deg[n];
    float acc0 = (h == 0) ? __half2float(hs2h[(size_t)n * 32 + ch]) : 0.0f;  // self
    float acc1 = 0.0f, acc2 = 0.0f, acc3 = 0.0f;
    int k = 0;
    for (; k + 7 < cnt; k += 8) {
        int ra = srcidx[s + k + h];
        int rb = srcidx[s + k + 2 + h];
        int rc = srcidx[s + k + 4 + h];
        int rd = srcidx[s + k + 6 + h];
        acc0 += __half2float(hs2h[(size_t)ra * 32 + ch]);
        acc1 += __half2float(hs2h[(size_t)rb * 32 + ch]);
        acc2 += __half2float(hs2h[(size_t)rc * 32 + ch]);
        acc3 += __half2float(hs2h[(size_t)rd * 32 + ch]);
    }
    for (; k + 1 < cnt; k += 2) {
        int r = srcidx[s + k + h];
        acc0 += __half2float(hs2h[(size_t)r * 32 + ch]);
    }
    if (k < cnt && h == 0) {
        int r = srcidx[s + k];
        acc0 += __half2float(hs2h[(size_t)r * 32 + ch]);
    }
    float acc = (acc0 + acc1) + (acc2 + acc3);
    acc += __shfl_xor(acc, 32);
    float h2 = fmaxf(fmaf(acc, dinv[n], sb2[ch]), 0.0f);

    // matmul: 64 lanes = 2 j-halves x (16 u-outputs + 16 v-outputs)
    int jh = L >> 5;
    int os = (L >> 4) & 1;               // 0 -> u, 1 -> v
    int i  = L & 15;
    const float* M = os ? sB : sA;
    float part = 0.0f;
#pragma unroll
    for (int t = 0; t < 16; ++t) {
        int j = jh * 16 + t;
        float hj = __shfl(h2, j);
        part = fmaf(hj, M[j * 16 + i], part);
    }
    part += __shfl_xor(part, 32);
    if (L < 32) {
        __half val = __float2half_rn(part);
        int ii = i & 7;
        __half* base = os ? ((i < 8) ? vA : vB) : ((i < 8) ? uA : uB);
        base[(size_t)n * 8 + ii] = val;
    }
}

__device__ inline void unpack4(const float2 f, float* o) {
    const __half2* h2 = (const __half2*)&f;
#pragma unroll
    for (int i = 0; i < 2; ++i) {
        float2 t = __half22float2(h2[i]);
        o[2 * i] = t.x; o[2 * i + 1] = t.y;
    }
}

// channel-split edge MLP pass. PASS=0: partial over ch 0-7 -> spart.
// PASS=1: add ch 8-15 + sigmoid -> out. Tables 3.2MB/pass = L2-resident.
template <int PASS>
__global__ void k_edge_half(const int* __restrict__ row, const int* __restrict__ col,
                            const float* __restrict__ ea,
                            const __half* __restrict__ ut, const __half* __restrict__ vt,
                            const float* __restrict__ mW1, const float* __restrict__ mb1,
                            const float* __restrict__ mW2,  const float* __restrict__ mb2,
                            float* __restrict__ spart, float* __restrict__ out, int E) {
    __shared__ float sC[8], sb1[8], sW2v[8], sb2s;
    if (threadIdx.x < 8) {
        int i = threadIdx.x + PASS * 8;
        sC[threadIdx.x]   = mW1[64 * 16 + i];
        sb1[threadIdx.x]  = mb1[i];
        sW2v[threadIdx.x] = mW2[i];
    }
    if (threadIdx.x == 0) sb2s = mb2[0];
    __syncthreads();
    int tid    = blockIdx.x * blockDim.x + threadIdx.x;
    int stride = gridDim.x * blockDim.x;
    for (int e0 = tid * 2; e0 < E; e0 += stride * 2) {
        bool two = (e0 + 1 < E);
        int2 r2 = *(const int2*)(row + e0);
        int2 c2 = *(const int2*)(col + e0);
        float2 a2 = *(const float2*)(ea + e0);
        float2 u0 = *(const float2*)(ut + (size_t)r2.x * 8);
        float2 v0 = *(const float2*)(vt + (size_t)c2.x * 8);
        float2 u1 = *(const float2*)(ut + (size_t)r2.y * 8);
        float2 v1 = *(const float2*)(vt + (size_t)c2.y * 8);
        float uf0[4], vf0[4], uf1[4], vf1[4];
        unpack4(u0, uf0); unpack4(v0, vf0);
        unpack4(u1, uf1); unpack4(v1, vf1);
        // second half of the 8 channels (bytes 8..15 of the 16B row)
        float2 u0b = *(const float2*)(ut + (size_t)r2.x * 8 + 4);
        float2 v0b = *(const float2*)(vt + (size_t)c2.x * 8 + 4);
        float2 u1b = *(const float2*)(ut + (size_t)r2.y * 8 + 4);
        float2 v1b = *(const float2*)(vt + (size_t)c2.y * 8 + 4);
        float uf0b[4], vf0b[4], uf1b[4], vf1b[4];
        unpack4(u0b, uf0b); unpack4(v0b, vf0b);
        unpack4(u1b, uf1b); unpack4(v1b, vf1b);
        float s0 = (PASS == 0) ? sb2s : spart[e0];
        float s1 = (PASS == 0) ? sb2s : (two ? spart[e0 + 1] : 0.0f);
#pragma unroll
        for (int i = 0; i < 4; ++i) {
            float t0 = fmaf(a2.x, sC[i], sb1[i]);
            float t1 = fmaf(a2.y, sC[i], sb1[i]);
            s0 = fmaf(fmaxf(uf0[i] + vf0[i] + t0, 0.0f), sW2v[i], s0);
            s1 = fmaf(fmaxf(uf1[i] + vf1[i] + t1, 0.0f), sW2v[i], s1);
        }
#pragma unroll
        for (int i = 0; i < 4; ++i) {
            float t0 = fmaf(a2.x, sC[i + 4], sb1[i + 4]);
            float t1 = fmaf(a2.y, sC[i + 4], sb1[i + 4]);
            s0 = fmaf(fmaxf(uf0b[i] + vf0b[i] + t0, 0.0f), sW2v[i + 4], s0);
            s1 = fmaf(fmaxf(uf1b[i] + vf1b[i] + t1, 0.0f), sW2v[i + 4], s1);
        }
        if (PASS == 0) {
            if (two) *(float2*)(spart + e0) = make_float2(s0, s1);
            else     spart[e0] = s0;
        } else {
            float o0 = 1.0f / (1.0f + expf(-s0));
            float o1 = 1.0f / (1.0f + expf(-s1));
            if (two) *(float2*)(out + e0) = make_float2(o0, o1);
            else     out[e0] = o0;
        }
    }
}

extern "C" void kernel_launch(void* const* d_in, const int* in_sizes, int n_in,
                              void* d_out, int out_size, void* d_ws, size_t ws_size,
                              hipStream_t stream) {
    const float* x   = (const float*)d_in[0];
    const int*   ei  = (const int*)d_in[1];
    const float* ea  = (const float*)d_in[2];
    const float* W1  = (const float*)d_in[4];
    const float* b1  = (const float*)d_in[5];
    const float* W2  = (const float*)d_in[6];
    const float* b2  = (const float*)d_in[7];
    const float* mW1 = (const float*)d_in[8];
    const float* mb1 = (const float*)d_in[9];
    const float* mW2 = (const float*)d_in[10];
    const float* mb2 = (const float*)d_in[11];
    float* out = (float*)d_out;

    int N = in_sizes[0] / 2;
    int E = in_sizes[2];
    const int* row = ei;
    const int* col = ei + E;

    int clog = 0; while ((1u << clog) < (unsigned)N) ++clog;
    int wshift = clog > 3 ? clog - 3 : 0;
    int nph = ((N - 1) >> wshift) + 1;

    int* deg    = (int*)d_ws;            // N
    int* start  = deg + N;               // N
    int* cursor = start + N;             // N
    int* bsum   = cursor + N;            // 1024
    int* srcidx = bsum + 1024;           // E
    float* dinv = (float*)(srcidx + E);  // N
    float* xs   = dinv + (size_t)N;      // 2N
    float* spart = xs + (size_t)2 * N;   // E
    __half* hs2h = (__half*)(spart + (size_t)E);    // 32N halves
    __half* uA   = hs2h + (size_t)32 * N;           // 8N halves
    __half* uB   = uA + (size_t)8 * N;              // 8N
    __half* vA   = uB + (size_t)8 * N;              // 8N
    __half* vB   = vA + (size_t)8 * N;              // 8N

    int nb_n = (N + 255) / 256;

    hipMemsetAsync(deg, 0, (size_t)N * sizeof(int), stream);
    k_count<<<2048, 256, 0, stream>>>(col, deg, E);
    k_scan1<<<nb_n, 256, 0, stream>>>(deg, start, bsum, N);
    k_scan2<<<1, 512, 0, stream>>>(bsum, nb_n);
    k_scan3<<<nb_n, 256, 0, stream>>>(start, bsum, cursor, deg, x, dinv, xs, N);
    k_fill <<<2048, 256, 0, stream>>>(row, col, cursor, srcidx, E, wshift, nph);
    k_l1l2 <<<nb_n, 256, 0, stream>>>(start, deg, srcidx, xs, dinv, W1, b1, W2, hs2h, N);
    k_agg2uv<<<(N + 3) / 4, 256, 0, stream>>>(start, deg, srcidx, hs2h, dinv, b2, mW1,
                                              uA, uB, vA, vB, N);
    k_edge_half<0><<<2048, 256, 0, stream>>>(row, col, ea, uA, vA, mW1, mb1, mW2, mb2,
                                             spart, out, E);
    k_edge_half<1><<<2048, 256, 0, stream>>>(row, col, ea, uB, vB, mW1, mb1, mW2, mb2,
                                             spart, out, E);
}

// Round 16
// 328.692 us; speedup vs baseline: 1.4892x; 1.1081x over previous
//
#include <hip/hip_runtime.h>
#include <hip/hip_fp16.h>
#include <math.h>

// ---------------------------------------------------------------------------
// GCN (2->64->32) + edge MLP (65->16->1), N=100k, E=1.6M.
// R16: atomic-free fill. k_count's atomicAdd return value IS the edge's
//   rank within its destination node -> store rank[e] (sequential write);
//   k_fill computes p = start[col] + rank[e] with NO atomics (was 1.6M
//   device-scope atomics = serialization at the coherence point).
//   Keep XCD-exclusive windowed fill for write locality; drop cursor.
// ---------------------------------------------------------------------------

__global__ void k_count(const int* __restrict__ col, int* __restrict__ deg,
                        int* __restrict__ rank, int E) {
    int stride = gridDim.x * blockDim.x;
    for (int e = blockIdx.x * blockDim.x + threadIdx.x; e < E; e += stride)
        rank[e] = atomicAdd(deg + col[e], 1);
}

__global__ void k_scan1(const int* __restrict__ deg, int* __restrict__ start,
                        int* __restrict__ bsum, int N) {
    __shared__ int sd[256];
    int t = threadIdx.x;
    int n = blockIdx.x * 256 + t;
    int d = (n < N) ? deg[n] : 0;
    sd[t] = d;
    __syncthreads();
    for (int off = 1; off < 256; off <<= 1) {
        int tv = (t >= off) ? sd[t - off] : 0;
        __syncthreads();
        sd[t] += tv;
        __syncthreads();
    }
    if (n < N) start[n] = sd[t] - d;
    if (t == 255) bsum[blockIdx.x] = sd[255];
}

__global__ void k_scan2(int* __restrict__ bsum, int nb) {
    __shared__ int sd[512];
    int t = threadIdx.x;
    int d = (t < nb) ? bsum[t] : 0;
    sd[t] = d;
    __syncthreads();
    for (int off = 1; off < 512; off <<= 1) {
        int tv = (t >= off) ? sd[t - off] : 0;
        __syncthreads();
        sd[t] += tv;
        __syncthreads();
    }
    if (t < nb) bsum[t] = sd[t] - d;
}

__global__ void k_scan3(int* __restrict__ start, const int* __restrict__ bsum,
                        const int* __restrict__ deg,
                        const float* __restrict__ x, float* __restrict__ dinv,
                        float* __restrict__ xs, int N) {
    int n = blockIdx.x * 256 + threadIdx.x;
    if (n >= N) return;
    int s = start[n] + bsum[blockIdx.x];
    start[n] = s;
    float di = rsqrtf((float)deg[n] + 1.0f);
    dinv[n] = di;
    xs[2 * n] = x[2 * n] * di;
    xs[2 * n + 1] = x[2 * n + 1] * di;
}

// atomic-free XCD-exclusive windowed fill: p = start[c] + rank[e]
__global__ void k_fill(const int* __restrict__ row, const int* __restrict__ col,
                       const int* __restrict__ rank, const int* __restrict__ start,
                       int* __restrict__ srcidx, int E, int wshift, int nph) {
    int g      = blockIdx.x & 7;
    int tid0   = (blockIdx.x >> 3) * blockDim.x + threadIdx.x;
    int stride = (gridDim.x >> 3) * blockDim.x;
    for (int ph = g; ph < nph; ph += 8) {
        for (int e = tid0; e < E; e += stride) {
            int c = col[e];
            if ((c >> wshift) == ph) {
                srcidx[start[c] + rank[e]] = row[e];
            }
        }
    }
}

// per node: agg xs (+self), *dinv, W1+b1, relu, W2, *dinv -> hs2h (fp16)
__global__ void k_l1l2(const int* __restrict__ start, const int* __restrict__ deg,
                       const int* __restrict__ srcidx,
                       const float* __restrict__ xs, const float* __restrict__ dinv,
                       const float* __restrict__ W1, const float* __restrict__ b1,
                       const float* __restrict__ W2,
                       __half* __restrict__ hs2h, int N) {
    __shared__ float sW1[128], sb1[64], sW2[2048];
    for (int i = threadIdx.x; i < 128;  i += blockDim.x) sW1[i] = W1[i];
    for (int i = threadIdx.x; i < 64;   i += blockDim.x) sb1[i] = b1[i];
    for (int i = threadIdx.x; i < 2048; i += blockDim.x) sW2[i] = W2[i];
    __syncthreads();
    int n = blockIdx.x * 256 + threadIdx.x;
    if (n >= N) return;
    int s = start[n], cnt = deg[n];
    float a0 = xs[2 * n], a1 = xs[2 * n + 1];
    for (int k = 0; k < cnt; ++k) {
        int r = srcidx[s + k];
        a0 += xs[2 * r];
        a1 += xs[2 * r + 1];
    }
    float di = dinv[n];
    a0 *= di; a1 *= di;
    float acc[32];
#pragma unroll
    for (int j = 0; j < 32; ++j) acc[j] = 0.0f;
    for (int k = 0; k < 64; ++k) {
        float h = fmaxf(fmaf(a0, sW1[k], fmaf(a1, sW1[64 + k], sb1[k])), 0.0f);
#pragma unroll
        for (int j = 0; j < 32; ++j) acc[j] = fmaf(h, sW2[k * 32 + j], acc[j]);
    }
    __half2 hb[16];
#pragma unroll
    for (int j = 0; j < 16; ++j)
        hb[j] = __floats2half2_rn(acc[2 * j] * di, acc[2 * j + 1] * di);
    float4* op = (float4*)(hs2h + (size_t)n * 32);
    const float4* ip = (const float4*)hb;
#pragma unroll
    for (int q = 0; q < 4; ++q) op[q] = ip[q];
}

// one 64-lane wave per node; halves h=0/1; 4-deep unroll (8 rows in flight);
// outputs split into lo/hi channel tables (uA/uB/vA/vB, 8 ch each)
__global__ void k_agg2uv(const int* __restrict__ start, const int* __restrict__ deg,
                         const int* __restrict__ srcidx,
                         const __half* __restrict__ hs2h, const float* __restrict__ dinv,
                         const float* __restrict__ b2, const float* __restrict__ mW1,
                         __half* __restrict__ uA, __half* __restrict__ uB,
                         __half* __restrict__ vA, __half* __restrict__ vB, int N) {
    __shared__ float sA[512], sB[512], sb2[32];
    for (int i = threadIdx.x; i < 512; i += 256) { sA[i] = mW1[i]; sB[i] = mW1[512 + i]; }
    if (threadIdx.x < 32) sb2[threadIdx.x] = b2[threadIdx.x];
    __syncthreads();
    int L  = threadIdx.x & 63;
    int w  = threadIdx.x >> 6;
    int ch = L & 31;
    int h  = L >> 5;
    int n  = blockIdx.x * 4 + w;
    if (n >= N) return;

    int s = start[n], cnt = deg[n];
    float acc0 = (h == 0) ? __half2float(hs2h[(size_t)n * 32 + ch]) : 0.0f;  // self
    float acc1 = 0.0f, acc2 = 0.0f, acc3 = 0.0f;
    int k = 0;
    for (; k + 7 < cnt; k += 8) {
        int ra = srcidx[s + k + h];
        int rb = srcidx[s + k + 2 + h];
        int rc = srcidx[s + k + 4 + h];
        int rd = srcidx[s + k + 6 + h];
        acc0 += __half2float(hs2h[(size_t)ra * 32 + ch]);
        acc1 += __half2float(hs2h[(size_t)rb * 32 + ch]);
        acc2 += __half2float(hs2h[(size_t)rc * 32 + ch]);
        acc3 += __half2float(hs2h[(size_t)rd * 32 + ch]);
    }
    for (; k + 1 < cnt; k += 2) {
        int r = srcidx[s + k + h];
        acc0 += __half2float(hs2h[(size_t)r * 32 + ch]);
    }
    if (k < cnt && h == 0) {
        int r = srcidx[s + k];
        acc0 += __half2float(hs2h[(size_t)r * 32 + ch]);
    }
    float acc = (acc0 + acc1) + (acc2 + acc3);
    acc += __shfl_xor(acc, 32);
    float h2 = fmaxf(fmaf(acc, dinv[n], sb2[ch]), 0.0f);

    // matmul: 64 lanes = 2 j-halves x (16 u-outputs + 16 v-outputs)
    int jh = L >> 5;
    int os = (L >> 4) & 1;               // 0 -> u, 1 -> v
    int i  = L & 15;
    const float* M = os ? sB : sA;
    float part = 0.0f;
#pragma unroll
    for (int t = 0; t < 16; ++t) {
        int j = jh * 16 + t;
        float hj = __shfl(h2, j);
        part = fmaf(hj, M[j * 16 + i], part);
    }
    part += __shfl_xor(part, 32);
    if (L < 32) {
        __half val = __float2half_rn(part);
        int ii = i & 7;
        __half* base = os ? ((i < 8) ? vA : vB) : ((i < 8) ? uA : uB);
        base[(size_t)n * 8 + ii] = val;
    }
}

__device__ inline void unpack4(const float2 f, float* o) {
    const __half2* h2 = (const __half2*)&f;
#pragma unroll
    for (int i = 0; i < 2; ++i) {
        float2 t = __half22float2(h2[i]);
        o[2 * i] = t.x; o[2 * i + 1] = t.y;
    }
}

// channel-split edge MLP pass. PASS=0: partial over ch 0-7 -> spart.
// PASS=1: add ch 8-15 + sigmoid -> out. Tables 3.2MB/pass = L2-resident.
template <int PASS>
__global__ void k_edge_half(const int* __restrict__ row, const int* __restrict__ col,
                            const float* __restrict__ ea,
                            const __half* __restrict__ ut, const __half* __restrict__ vt,
                            const float* __restrict__ mW1, const float* __restrict__ mb1,
                            const float* __restrict__ mW2,  const float* __restrict__ mb2,
                            float* __restrict__ spart, float* __restrict__ out, int E) {
    __shared__ float sC[8], sb1[8], sW2v[8], sb2s;
    if (threadIdx.x < 8) {
        int i = threadIdx.x + PASS * 8;
        sC[threadIdx.x]   = mW1[64 * 16 + i];
        sb1[threadIdx.x]  = mb1[i];
        sW2v[threadIdx.x] = mW2[i];
    }
    if (threadIdx.x == 0) sb2s = mb2[0];
    __syncthreads();
    int tid    = blockIdx.x * blockDim.x + threadIdx.x;
    int stride = gridDim.x * blockDim.x;
    for (int e0 = tid * 2; e0 < E; e0 += stride * 2) {
        bool two = (e0 + 1 < E);
        int2 r2 = *(const int2*)(row + e0);
        int2 c2 = *(const int2*)(col + e0);
        float2 a2 = *(const float2*)(ea + e0);
        float2 u0 = *(const float2*)(ut + (size_t)r2.x * 8);
        float2 v0 = *(const float2*)(vt + (size_t)c2.x * 8);
        float2 u1 = *(const float2*)(ut + (size_t)r2.y * 8);
        float2 v1 = *(const float2*)(vt + (size_t)c2.y * 8);
        float uf0[4], vf0[4], uf1[4], vf1[4];
        unpack4(u0, uf0); unpack4(v0, vf0);
        unpack4(u1, uf1); unpack4(v1, vf1);
        float2 u0b = *(const float2*)(ut + (size_t)r2.x * 8 + 4);
        float2 v0b = *(const float2*)(vt + (size_t)c2.x * 8 + 4);
        float2 u1b = *(const float2*)(ut + (size_t)r2.y * 8 + 4);
        float2 v1b = *(const float2*)(vt + (size_t)c2.y * 8 + 4);
        float uf0b[4], vf0b[4], uf1b[4], vf1b[4];
        unpack4(u0b, uf0b); unpack4(v0b, vf0b);
        unpack4(u1b, uf1b); unpack4(v1b, vf1b);
        float s0 = (PASS == 0) ? sb2s : spart[e0];
        float s1 = (PASS == 0) ? sb2s : (two ? spart[e0 + 1] : 0.0f);
#pragma unroll
        for (int i = 0; i < 4; ++i) {
            float t0 = fmaf(a2.x, sC[i], sb1[i]);
            float t1 = fmaf(a2.y, sC[i], sb1[i]);
            s0 = fmaf(fmaxf(uf0[i] + vf0[i] + t0, 0.0f), sW2v[i], s0);
            s1 = fmaf(fmaxf(uf1[i] + vf1[i] + t1, 0.0f), sW2v[i], s1);
        }
#pragma unroll
        for (int i = 0; i < 4; ++i) {
            float t0 = fmaf(a2.x, sC[i + 4], sb1[i + 4]);
            float t1 = fmaf(a2.y, sC[i + 4], sb1[i + 4]);
            s0 = fmaf(fmaxf(uf0b[i] + vf0b[i] + t0, 0.0f), sW2v[i + 4], s0);
            s1 = fmaf(fmaxf(uf1b[i] + vf1b[i] + t1, 0.0f), sW2v[i + 4], s1);
        }
        if (PASS == 0) {
            if (two) *(float2*)(spart + e0) = make_float2(s0, s1);
            else     spart[e0] = s0;
        } else {
            float o0 = 1.0f / (1.0f + expf(-s0));
            float o1 = 1.0f / (1.0f + expf(-s1));
            if (two) *(float2*)(out + e0) = make_float2(o0, o1);
            else     out[e0] = o0;
        }
    }
}

extern "C" void kernel_launch(void* const* d_in, const int* in_sizes, int n_in,
                              void* d_out, int out_size, void* d_ws, size_t ws_size,
                              hipStream_t stream) {
    const float* x   = (const float*)d_in[0];
    const int*   ei  = (const int*)d_in[1];
    const float* ea  = (const float*)d_in[2];
    const float* W1  = (const float*)d_in[4];
    const float* b1  = (const float*)d_in[5];
    const float* W2  = (const float*)d_in[6];
    const float* b2  = (const float*)d_in[7];
    const float* mW1 = (const float*)d_in[8];
    const float* mb1 = (const float*)d_in[9];
    const float* mW2 = (const float*)d_in[10];
    const float* mb2 = (const float*)d_in[11];
    float* out = (float*)d_out;

    int N = in_sizes[0] / 2;
    int E = in_sizes[2];
    const int* row = ei;
    const int* col = ei + E;

    int clog = 0; while ((1u << clog) < (unsigned)N) ++clog;
    int wshift = clog > 3 ? clog - 3 : 0;
    int nph = ((N - 1) >> wshift) + 1;

    int* deg    = (int*)d_ws;            // N
    int* start  = deg + N;               // N
    int* bsum   = start + N;             // 1024
    int* rank   = bsum + 1024;           // E
    int* srcidx = rank + E;              // E
    float* dinv = (float*)(srcidx + E);  // N
    float* xs   = dinv + (size_t)N;      // 2N
    float* spart = xs + (size_t)2 * N;   // E
    __half* hs2h = (__half*)(spart + (size_t)E);    // 32N halves
    __half* uA   = hs2h + (size_t)32 * N;           // 8N halves
    __half* uB   = uA + (size_t)8 * N;              // 8N
    __half* vA   = uB + (size_t)8 * N;              // 8N
    __half* vB   = vA + (size_t)8 * N;              // 8N

    int nb_n = (N + 255) / 256;

    hipMemsetAsync(deg, 0, (size_t)N * sizeof(int), stream);
    k_count<<<2048, 256, 0, stream>>>(col, deg, rank, E);
    k_scan1<<<nb_n, 256, 0, stream>>>(deg, start, bsum, N);
    k_scan2<<<1, 512, 0, stream>>>(bsum, nb_n);
    k_scan3<<<nb_n, 256, 0, stream>>>(start, bsum, deg, x, dinv, xs, N);
    k_fill <<<2048, 256, 0, stream>>>(row, col, rank, start, srcidx, E, wshift, nph);
    k_l1l2 <<<nb_n, 256, 0, stream>>>(start, deg, srcidx, xs, dinv, W1, b1, W2, hs2h, N);
    k_agg2uv<<<(N + 3) / 4, 256, 0, stream>>>(start, deg, srcidx, hs2h, dinv, b2, mW1,
                                              uA, uB, vA, vB, N);
    k_edge_half<0><<<2048, 256, 0, stream>>>(row, col, ea, uA, vA, mW1, mb1, mW2, mb2,
                                             spart, out, E);
    k_edge_half<1><<<2048, 256, 0, stream>>>(row, col, ea, uB, vB, mW1, mb1, mW2, mb2,
                                             spart, out, E);
}